// Round 13
// baseline (1166.886 us; speedup 1.0000x reference)
//
#include <hip/hip_runtime.h>
#include <hip/hip_bf16.h>

#define BQ   2
#define NH   12
#define SEQ  2048
#define DIM  64
#define EXQ  64   // end_x (both grids equal -> resample is identity)

#define TENSOR_ELEMS ((size_t)BQ * NH * SEQ * DIM)   // 3,145,728 bf16 each
#define PERS_BLOCKS  512                              // 2 blocks/CU exact
#define TILES_PER_BLOCK 12                            // 512*12 = 6144 tiles
#define NPAIRS       12                               // head-pairs (2 bh each)
#define UNITS_PER_PAIR 131072                         // float4-units per pair

typedef __attribute__((ext_vector_type(8))) short short8;
typedef __attribute__((ext_vector_type(4))) float f32x4;

static __device__ __forceinline__ unsigned int pk2bf(float lo, float hi) {
    union { float f; unsigned int u; } a, b; a.f = lo; b.f = hi;
    unsigned int rl = (a.u + 0x7fffu + ((a.u >> 16) & 1u)) >> 16;  // RNE
    unsigned int rh = (b.u + 0x7fffu + ((b.u >> 16) & 1u)) >> 16;
    return (rh << 16) | (rl & 0xffffu);
}

// barrier that does NOT drain vmcnt (plain __syncthreads emits vmcnt(0),
// which would stall on our fire-and-forget store stream)
static __device__ __forceinline__ void wg_barrier_lds() {
    asm volatile("s_waitcnt lgkmcnt(0)" ::: "memory");
    __builtin_amdgcn_s_barrier();
}

// ---- Fused persistent kernel: pipelined RoPE + 128x128 MFMA GEMM + decay ---
// 512 co-resident blocks (2/CU, LDS-bound). Iteration-major tile mapping
// (g = t*512 + blk) -> iteration t uses head-pair t (bh 2t,2t+1). Rope for
// pair p is done cooperatively by all blocks during iteration p-3 (pairs
// 0-2 upfront), published via device-scope counters; blocks spin (acquire)
// on pair t+1 before prefetching its panels. Rope rides the idle read BW
// under the store drain, eliminating the ~13us serial rope kernel.
// Safety: bounded spin -> idempotent self-compute fallback (no deadlock
// even if co-residency breaks). Counters zeroed per launch via memsetAsync.
__global__ __launch_bounds__(256, 2)
void fused_kernel(const float* __restrict__ qin,
                  const float* __restrict__ bin,
                  const float* __restrict__ freqs,   // [2, NH, 16]
                  const float* __restrict__ weight,  // [NH]
                  unsigned int* __restrict__ ws_u32, // bf16 xq|xb as uint pairs
                  int* __restrict__ counters,        // [NPAIRS]
                  float* __restrict__ out)
{
    __shared__ float lds[128 * 128];      // 64 KB stage

    const int lane = threadIdx.x & 63;
    const int wave = threadIdx.x >> 6;
    const int wr   = wave >> 1, wc = wave & 1;
    const int r16  = lane & 15;
    const int kg   = lane >> 4;
    const int c32  = lane & 31;

    const unsigned short* xq = (const unsigned short*)ws_u32;
    const unsigned short* xb = xq + TENSOR_ELEMS;

    short8 afr[2][4], bfr[2][4];

    // ---- rope one float4-unit range of head-pair p (idempotent) ----
    auto rope_units = [&](int p, int u0, int u1) {
        for (int u = u0 + (int)threadIdx.x; u < u1; u += 256) {
            int d4     = u & 15;
            int n      = (u >> 4) & 2047;
            int bhp    = (u >> 15) & 1;
            int tensor = u >> 16;
            int bh     = 2 * p + bhp;
            int h      = bh % NH;
            const float* src = tensor ? bin : qin;
            float4 v = *reinterpret_cast<const float4*>(
                src + (size_t)bh * (SEQ * DIM) + n * DIM + d4 * 4);
            float f0, f1, coord;
            if (d4 < 8) {
                f0 = freqs[h * 16 + 2 * d4];
                f1 = freqs[h * 16 + 2 * d4 + 1];
                coord = (float)(n & (EXQ - 1));
            } else {
                f0 = freqs[NH * 16 + h * 16 + 2 * d4 - 16];
                f1 = freqs[NH * 16 + h * 16 + 2 * d4 - 15];
                coord = (float)(n >> 6);
            }
            float s0 = __sinf(f0 * coord), c0 = __cosf(f0 * coord);
            float s1 = __sinf(f1 * coord), c1 = __cosf(f1 * coord);
            uint2 pk;
            pk.x = pk2bf(v.x * c0 - v.y * s0, v.x * s0 + v.y * c0);
            pk.y = pk2bf(v.z * c1 - v.w * s1, v.z * s1 + v.w * c1);
            *reinterpret_cast<uint2*>(ws_u32 + (size_t)tensor * (TENSOR_ELEMS / 2)
                                      + bh * (SEQ * DIM / 2) + n * 32 + d4 * 2) = pk;
        }
    };

    // ---- wait until pair p fully roped (all 512 contributions) ----
    auto wait_pair = [&](int p) {
        const int* cp = counters + p;
        int polls = 0;
        while (__hip_atomic_load(cp, __ATOMIC_ACQUIRE,
                                 __HIP_MEMORY_SCOPE_AGENT) < PERS_BLOCKS) {
            if (++polls > 200000) {          // co-residency broken: self-compute
                rope_units(p, 0, UNITS_PER_PAIR);
                break;
            }
        }
    };

    // ---- load fragments for tile g ----
    auto load_frags = [&](int g) {
        int bh = g >> 8, rem = g & 255;
        int trow = rem >> 4, tcol = rem & 15;
        const size_t base = (size_t)bh * SEQ * DIM;
        int row0 = trow * 128 + wr * 64;
        int col0 = tcol * 128 + wc * 64;
#pragma unroll
        for (int kk = 0; kk < 2; ++kk)
#pragma unroll
            for (int i = 0; i < 4; ++i) {
                int arw = row0 + i * 16 + r16;
                int bcl = col0 + i * 16 + r16;
                afr[kk][i] = *reinterpret_cast<const short8*>(
                    xq + base + (size_t)arw * DIM + kk * 32 + kg * 8);
                bfr[kk][i] = *reinterpret_cast<const short8*>(
                    xb + base + (size_t)bcl * DIM + kk * 32 + kg * 8);
            }
    };

    const int myslice0 = (int)blockIdx.x * 256;

    // ---- preloop: rope pairs 0..2, publish, then load iter-0 frags ----
    rope_units(0, myslice0, myslice0 + 256);
    rope_units(1, myslice0, myslice0 + 256);
    rope_units(2, myslice0, myslice0 + 256);
    __threadfence();
    __syncthreads();
    if (threadIdx.x == 0) {
        atomicAdd(counters + 0, 1);
        atomicAdd(counters + 1, 1);
        atomicAdd(counters + 2, 1);
    }
    wait_pair(0);
    load_frags(blockIdx.x);

    for (int t = 0; t < TILES_PER_BLOCK; ++t) {
        const int g    = t * PERS_BLOCKS + blockIdx.x;   // iteration-major
        const int bh   = g >> 8, rem = g & 255;
        const int trow = rem >> 4, tcol = rem & 15;
        const int h    = bh % NH;
        const int brow0 = trow * 128, bcol0 = tcol * 128;

        // ---- MFMA (swapped operands -> lane holds 4 consecutive cols) ----
        f32x4 acc[4][4];
#pragma unroll
        for (int i = 0; i < 4; ++i)
#pragma unroll
            for (int j = 0; j < 4; ++j)
                acc[i][j] = (f32x4){0.f, 0.f, 0.f, 0.f};
#pragma unroll
        for (int kk = 0; kk < 2; ++kk)
#pragma unroll
            for (int i = 0; i < 4; ++i)
#pragma unroll
                for (int j = 0; j < 4; ++j)
                    acc[i][j] = __builtin_amdgcn_mfma_f32_16x16x32_bf16(
                        bfr[kk][j], afr[kk][i], acc[i][j], 0, 0, 0);

        // ---- in-register decay: 7 shared windows T[d], d = j-i+3 ----
        {
            float w  = weight[h];
            float lw = w > 0.f ? w : 0.01f * w;
            float scale = -lw * 1.44269504088896f;
            float fdy = (float)(2 * (tcol - trow) + (wc - wr));
            float dy2 = fdy * fdy;
            f32x4 T[7];
#pragma unroll
            for (int d = 0; d < 7; ++d) {
                float dx0 = (float)((d - 3) * 16 + kg * 4 - r16);
#pragma unroll
                for (int w_ = 0; w_ < 4; ++w_) {
                    float dx = dx0 + (float)w_;
                    float dist = __builtin_amdgcn_sqrtf(dx * dx + dy2);
                    T[d][w_] = __builtin_amdgcn_exp2f(scale * dist);
                }
            }
#pragma unroll
            for (int i = 0; i < 4; ++i)
#pragma unroll
                for (int j = 0; j < 4; ++j)
                    acc[i][j] *= T[j - i + 3];
        }

        // ---- pipeline: wait+prefetch next pair, rope pair t+3, publish ----
        if (t + 1 < TILES_PER_BLOCK) {
            wait_pair(t + 1);
            load_frags((t + 1) * PERS_BLOCKS + blockIdx.x);
        }
        if (t + 3 < NPAIRS) {
            rope_units(t + 3, myslice0, myslice0 + 256);
            __threadfence();
            __syncthreads();              // all block's rope writes retired
            if (threadIdx.x == 0) atomicAdd(counters + t + 3, 1);
        } else {
            wg_barrier_lds();             // prev drain reads complete
        }
        __builtin_amdgcn_sched_barrier(0);

        // ---- stage to LDS (swizzled) ----
#pragma unroll
        for (int i = 0; i < 4; ++i) {
            int lrow = wr * 64 + i * 16 + r16;       // 0..127
#pragma unroll
            for (int j = 0; j < 4; ++j) {
                int slot = (wc * 16 + j * 4 + kg) ^ (lrow & 7);
                *reinterpret_cast<f32x4*>(&lds[lrow * 128 + slot * 4]) = acc[i][j];
            }
        }
        wg_barrier_lds();                 // stage visible to all waves

        // ---- drain: 16 instrs/wave, each 2 rows x 512 B contiguous ----
        const size_t obase = (size_t)bh * SEQ * SEQ;
#pragma unroll
        for (int tI = 0; tI < 16; ++tI) {
            int lr = wave * 32 + tI * 2 + (lane >> 5);   // 0..127
            int slot = c32 ^ (lr & 7);
            f32x4 v = *reinterpret_cast<const f32x4*>(&lds[lr * 128 + slot * 4]);
            float* op = out + obase + (size_t)(brow0 + lr) * SEQ + bcol0 + c32 * 4;
            *reinterpret_cast<f32x4*>(op) = v;           // plain store
        }
    }
}

extern "C" void kernel_launch(void* const* d_in, const int* in_sizes, int n_in,
                              void* d_out, int out_size, void* d_ws, size_t ws_size,
                              hipStream_t stream) {
    const float* q  = (const float*)d_in[0];
    const float* b  = (const float*)d_in[1];
    const float* fr = (const float*)d_in[2];
    const float* wt = (const float*)d_in[3];
    float* out = (float*)d_out;

    const size_t need = 2 * TENSOR_ELEMS * sizeof(unsigned short)
                      + NPAIRS * sizeof(int);
    if (ws_size < need) return;

    unsigned int* ws_u32 = (unsigned int*)d_ws;
    int* counters = (int*)((unsigned short*)d_ws + 2 * TENSOR_ELEMS);

    hipMemsetAsync(counters, 0, NPAIRS * sizeof(int), stream);
    fused_kernel<<<PERS_BLOCKS, 256, 0, stream>>>(q, b, fr, wt,
                                                  ws_u32, counters, out);
}

// Round 14
// 224.945 us; speedup vs baseline: 5.1874x; 5.1874x over previous
//
#include <hip/hip_runtime.h>
#include <hip/hip_bf16.h>

#define BQ   2
#define NH   12
#define SEQ  2048
#define DIM  64
#define EXQ  64   // end_x (both grids equal -> resample is identity)

#define PERS_BLOCKS  512                              // 2 blocks/CU exact
#define TILES_PER_BLOCK 12                            // 512*12 = 6144 tiles

typedef __attribute__((ext_vector_type(8))) short short8;
typedef __attribute__((ext_vector_type(4))) float f32x4;

static __device__ __forceinline__ unsigned int pk2bf(float lo, float hi) {
    union { float f; unsigned int u; } a, b; a.f = lo; b.f = hi;
    unsigned int rl = (a.u + 0x7fffu + ((a.u >> 16) & 1u)) >> 16;  // RNE
    unsigned int rh = (b.u + 0x7fffu + ((b.u >> 16) & 1u)) >> 16;
    return (rh << 16) | (rl & 0xffffu);
}

// barrier that does NOT drain vmcnt (plain __syncthreads emits vmcnt(0),
// which would stall on our fire-and-forget store stream)
static __device__ __forceinline__ void wg_barrier_lds() {
    asm volatile("s_waitcnt lgkmcnt(0)" ::: "memory");
    __builtin_amdgcn_s_barrier();
}

// ---- Fused single kernel: RoPE-in-register + 128x128 MFMA GEMM + decay -----
// ITERATION-MAJOR mapping (g = t*512 + blk): at iteration t all 512 blocks
// work on heads 2t/2t+1, so the fp32 q/b panel working set is ~2 MB device-
// wide and each panel's 16 sharers read it CONCURRENTLY (R12's proven
// insight) -> first toucher misses to HBM (~50 MB total), rest hit L3/L2
// inside the iteration window, before the 33 MB/iter write stream can wash
// it (R11 failed only because its block-major mapping spread sharers over
// the whole kernel). No ws, no rope kernel, no cross-block sync (R13's
// lesson). Rotation: each lane's 8 k-values = 4 pairs; kk=0 -> x-axis
// (coord=row&63), kk=1 -> y-axis (coord=row>>6); fast __sinf/__cosf.
// Rest identical to R12: swapped-operand MFMA, 7-window decay (v_sqrt/
// v_exp), 64 KB LDS transpose stage (XOR swizzle), lane-contiguous plain
// f32x4 stores, lgkm-only barriers, prefetch-before-stores.
__global__ __launch_bounds__(256, 2)
void fused_gemm_kernel(const float* __restrict__ qin,
                       const float* __restrict__ bin,
                       const float* __restrict__ freqs,   // [2, NH, 16]
                       const float* __restrict__ weight,  // [NH]
                       float* __restrict__ out)
{
    __shared__ float lds[128 * 128];      // 64 KB stage

    const int lane = threadIdx.x & 63;
    const int wave = threadIdx.x >> 6;
    const int wr   = wave >> 1, wc = wave & 1;
    const int r16  = lane & 15;
    const int kg   = lane >> 4;
    const int c32  = lane & 31;

    short8 afr[2][4], bfr[2][4];
    float ffx[4], ffy[4];                 // this lane's freq slice (kg*4+j)

    auto update_freqs = [&](int h) {
#pragma unroll
        for (int j = 0; j < 4; ++j) {
            ffx[j] = freqs[h * 16 + kg * 4 + j];
            ffy[j] = freqs[NH * 16 + h * 16 + kg * 4 + j];
        }
    };

    // load 8 fp32 k-values of one row, rotate, pack to bf16 frag
    auto rotate_frag = [&](const float* src, int bh, int row, int kk) -> short8 {
        const float* p = src + ((size_t)bh * SEQ + row) * DIM + kk * 32 + kg * 8;
        float4 va = *reinterpret_cast<const float4*>(p);
        float4 vb = *reinterpret_cast<const float4*>(p + 4);
        float coord = kk ? (float)(row >> 6) : (float)(row & (EXQ - 1));
        float x0[4] = {va.x, va.z, vb.x, vb.z};
        float x1[4] = {va.y, va.w, vb.y, vb.w};
        union { unsigned int u[4]; short8 s; } r;
#pragma unroll
        for (int j = 0; j < 4; ++j) {
            float f = kk ? ffy[j] : ffx[j];
            float ang = coord * f;
            float s = __sinf(ang), c = __cosf(ang);
            r.u[j] = pk2bf(x0[j] * c - x1[j] * s, x0[j] * s + x1[j] * c);
        }
        return r.s;
    };

    // ---- load + rotate all fragments for tile g ----
    auto load_frags = [&](int g) {
        int bh = g >> 8, rem = g & 255;
        int trow = rem >> 4, tcol = rem & 15;
        update_freqs(bh % NH);
        int row0 = trow * 128 + wr * 64;
        int col0 = tcol * 128 + wc * 64;
#pragma unroll
        for (int kk = 0; kk < 2; ++kk)
#pragma unroll
            for (int i = 0; i < 4; ++i) {
                afr[kk][i] = rotate_frag(qin, bh, row0 + i * 16 + r16, kk);
                bfr[kk][i] = rotate_frag(bin, bh, col0 + i * 16 + r16, kk);
            }
    };

    load_frags(blockIdx.x);

    for (int t = 0; t < TILES_PER_BLOCK; ++t) {
        const int g    = t * PERS_BLOCKS + blockIdx.x;   // iteration-major
        const int bh   = g >> 8, rem = g & 255;
        const int trow = rem >> 4, tcol = rem & 15;
        const int h    = bh % NH;
        const int brow0 = trow * 128, bcol0 = tcol * 128;

        // ---- MFMA (swapped operands -> lane holds 4 consecutive cols) ----
        f32x4 acc[4][4];
#pragma unroll
        for (int i = 0; i < 4; ++i)
#pragma unroll
            for (int j = 0; j < 4; ++j)
                acc[i][j] = (f32x4){0.f, 0.f, 0.f, 0.f};
#pragma unroll
        for (int kk = 0; kk < 2; ++kk)
#pragma unroll
            for (int i = 0; i < 4; ++i)
#pragma unroll
                for (int j = 0; j < 4; ++j)
                    acc[i][j] = __builtin_amdgcn_mfma_f32_16x16x32_bf16(
                        bfr[kk][j], afr[kk][i], acc[i][j], 0, 0, 0);

        // ---- prefetch+rotate next tile's fragments (hides L3/L2 latency
        //      under the decay VALU below and the other block's drain) ----
        if (t + 1 < TILES_PER_BLOCK)
            load_frags((t + 1) * PERS_BLOCKS + blockIdx.x);

        // ---- in-register decay: 7 shared windows T[d], d = j-i+3 ----
        {
            float w  = weight[h];
            float lw = w > 0.f ? w : 0.01f * w;
            float scale = -lw * 1.44269504088896f;
            float fdy = (float)(2 * (tcol - trow) + (wc - wr));
            float dy2 = fdy * fdy;
            f32x4 T[7];
#pragma unroll
            for (int d = 0; d < 7; ++d) {
                float dx0 = (float)((d - 3) * 16 + kg * 4 - r16);
#pragma unroll
                for (int w_ = 0; w_ < 4; ++w_) {
                    float dx = dx0 + (float)w_;
                    float dist = __builtin_amdgcn_sqrtf(dx * dx + dy2);
                    T[d][w_] = __builtin_amdgcn_exp2f(scale * dist);
                }
            }
#pragma unroll
            for (int i = 0; i < 4; ++i)
#pragma unroll
                for (int j = 0; j < 4; ++j)
                    acc[i][j] *= T[j - i + 3];
        }
        __builtin_amdgcn_sched_barrier(0);   // keep loads/rotate above stores

        // ---- stage to LDS (swizzled) ----
        wg_barrier_lds();                    // prev drain reads complete
#pragma unroll
        for (int i = 0; i < 4; ++i) {
            int lrow = wr * 64 + i * 16 + r16;       // 0..127
#pragma unroll
            for (int j = 0; j < 4; ++j) {
                int slot = (wc * 16 + j * 4 + kg) ^ (lrow & 7);
                *reinterpret_cast<f32x4*>(&lds[lrow * 128 + slot * 4]) = acc[i][j];
            }
        }
        wg_barrier_lds();                    // stage visible to all waves

        // ---- drain: 16 instrs/wave, each 2 rows x 512 B contiguous ----
        const size_t obase = (size_t)bh * SEQ * SEQ;
#pragma unroll
        for (int tI = 0; tI < 16; ++tI) {
            int lr = wave * 32 + tI * 2 + (lane >> 5);   // 0..127
            int slot = c32 ^ (lr & 7);
            f32x4 v = *reinterpret_cast<const f32x4*>(&lds[lr * 128 + slot * 4]);
            float* op = out + obase + (size_t)(brow0 + lr) * SEQ + bcol0 + c32 * 4;
            *reinterpret_cast<f32x4*>(op) = v;           // plain store
        }
    }
}

extern "C" void kernel_launch(void* const* d_in, const int* in_sizes, int n_in,
                              void* d_out, int out_size, void* d_ws, size_t ws_size,
                              hipStream_t stream) {
    const float* q  = (const float*)d_in[0];
    const float* b  = (const float*)d_in[1];
    const float* fr = (const float*)d_in[2];
    const float* wt = (const float*)d_in[3];
    float* out = (float*)d_out;

    fused_gemm_kernel<<<PERS_BLOCKS, 256, 0, stream>>>(q, b, fr, wt, out);
}

// Round 15
// 196.777 us; speedup vs baseline: 5.9300x; 1.1431x over previous
//
#include <hip/hip_runtime.h>
#include <hip/hip_bf16.h>

#define BQ   2
#define NH   12
#define SEQ  2048
#define DIM  64
#define EXQ  64   // end_x (both grids equal -> resample is identity)

#define TENSOR_ELEMS ((size_t)BQ * NH * SEQ * DIM)   // 3,145,728 bf16 each
#define ROPE_BLOCKS  6144                             // 2*BQ*NH*SEQ*16 / 256
#define PERS_BLOCKS  1024                             // 4 blocks/CU (32 KB LDS)
#define TILES_PER_BLOCK 6                             // 1024*6 = 6144 tiles

typedef __attribute__((ext_vector_type(8))) short short8;
typedef __attribute__((ext_vector_type(4))) float f32x4;

static __device__ __forceinline__ unsigned int pk2bf(float lo, float hi) {
    union { float f; unsigned int u; } a, b; a.f = lo; b.f = hi;
    unsigned int rl = (a.u + 0x7fffu + ((a.u >> 16) & 1u)) >> 16;  // RNE
    unsigned int rh = (b.u + 0x7fffu + ((b.u >> 16) & 1u)) >> 16;
    return (rh << 16) | (rl & 0xffffu);
}

// barrier that does NOT drain vmcnt (plain __syncthreads emits vmcnt(0),
// which would stall on our fire-and-forget store stream)
static __device__ __forceinline__ void wg_barrier_lds() {
    asm volatile("s_waitcnt lgkmcnt(0)" ::: "memory");
    __builtin_amdgcn_s_barrier();
}

// ---- Phase 1: RoPE-rotate q,b -> bf16 ws (fast HW trig) --------------------
// ws layout: xq bf16[TENSOR_ELEMS] | xb bf16[TENSOR_ELEMS]
__global__ __launch_bounds__(256)
void rope_kernel(const float* __restrict__ qin,
                 const float* __restrict__ bin,
                 const float* __restrict__ freqs,   // [2, NH, 16]
                 unsigned int* __restrict__ ws_u32)
{
    int t  = blockIdx.x * 256 + threadIdx.x;
    int p4 = t & 15;                 // quad of elements (2 pairs)
    int n  = (t >> 4) & (SEQ - 1);
    int rest = t >> 15;              // (tensor*BQ+b)*NH + h
    int h    = rest % NH;
    int tb   = rest / NH;
    int tensor = tb >> 1;
    int b      = tb & 1;

    float tx = (float)(n & (EXQ - 1));
    float ty = (float)(n >> 6);

    int pr0 = 2 * p4;                // pair indices pr0, pr0+1
    float f0, f1;
    if (p4 < 8) {
        f0 = freqs[h * 16 + pr0] * tx;
        f1 = freqs[h * 16 + pr0 + 1] * tx;
    } else {
        f0 = freqs[NH * 16 + h * 16 + (pr0 - 16)] * ty;
        f1 = freqs[NH * 16 + h * 16 + (pr0 - 15)] * ty;
    }

    const float* src = tensor ? bin : qin;
    size_t off = ((size_t)(b * NH + h) * SEQ + n) * DIM + 4 * p4;
    float4 v = *reinterpret_cast<const float4*>(src + off);

    float s0 = __sinf(f0), c0 = __cosf(f0);   // v_sin/v_cos fast path
    float s1 = __sinf(f1), c1 = __cosf(f1);

    float o0 = v.x * c0 - v.y * s0;
    float o1 = v.x * s0 + v.y * c0;
    float o2 = v.z * c1 - v.w * s1;
    float o3 = v.z * s1 + v.w * c1;

    uint2 packed;
    packed.x = pk2bf(o0, o1);
    packed.y = pk2bf(o2, o3);
    size_t uidx = (size_t)tensor * (TENSOR_ELEMS / 2) + (off >> 1);
    *reinterpret_cast<uint2*>(ws_u32 + uidx) = packed;
}

// ---- Phase 2: persistent 128x128 MFMA GEMM + decay, 4 blocks/CU ------------
// R12 structure with DEEPER WRITE PIPELINE: 32 KB LDS stage (tile drained in
// two 64-row halves, R5's verified mapping) -> 4 blocks/CU co-resident, so
// ~3 compute blocks cover every draining block and the CU's store stream is
// near-continuous (fill-kernel counters prove writes saturate at low
// occupancy when issue is continuous). Iteration-major mapping (g = t*1024
// + blk): iteration t covers heads 4t..4t+3, working set ~2 MB -> panel
// sharers stay concurrent (R12's proven insight). Swapped-operand MFMA,
// in-register 7-window decay (v_sqrt/v_exp), plain f32x4 stores, lgkm-only
// barriers, prefetch-before-stores.
__global__ __launch_bounds__(256, 4)
void gemm_delta_kernel(const unsigned short* __restrict__ ws,
                       const float* __restrict__ weight,
                       float* __restrict__ out)
{
    __shared__ float lds[64 * 128];       // 32 KB half-tile stage

    const int lane = threadIdx.x & 63;
    const int wave = threadIdx.x >> 6;
    const int wr   = wave >> 1, wc = wave & 1;
    const int r16  = lane & 15;
    const int kg   = lane >> 4;
    const int c32  = lane & 31;

    const unsigned short* xq = ws;
    const unsigned short* xb = ws + TENSOR_ELEMS;

    short8 afr[2][4], bfr[2][4];

    // ---- load fragments for tile g ----
    auto load_frags = [&](int g) {
        int bh = g >> 8, rem = g & 255;
        int trow = rem >> 4, tcol = rem & 15;
        const size_t base = (size_t)bh * SEQ * DIM;
        int row0 = trow * 128 + wr * 64;
        int col0 = tcol * 128 + wc * 64;
#pragma unroll
        for (int kk = 0; kk < 2; ++kk)
#pragma unroll
            for (int i = 0; i < 4; ++i) {
                int arw = row0 + i * 16 + r16;
                int bcl = col0 + i * 16 + r16;
                afr[kk][i] = *reinterpret_cast<const short8*>(
                    xq + base + (size_t)arw * DIM + kk * 32 + kg * 8);
                bfr[kk][i] = *reinterpret_cast<const short8*>(
                    xb + base + (size_t)bcl * DIM + kk * 32 + kg * 8);
            }
    };

    load_frags(blockIdx.x);

    for (int t = 0; t < TILES_PER_BLOCK; ++t) {
        const int g    = t * PERS_BLOCKS + blockIdx.x;   // iteration-major
        const int bh   = g >> 8, rem = g & 255;
        const int trow = rem >> 4, tcol = rem & 15;
        const int h    = bh % NH;
        const int brow0 = trow * 128, bcol0 = tcol * 128;

        // ---- MFMA (swapped operands -> lane holds 4 consecutive cols) ----
        f32x4 acc[4][4];
#pragma unroll
        for (int i = 0; i < 4; ++i)
#pragma unroll
            for (int j = 0; j < 4; ++j)
                acc[i][j] = (f32x4){0.f, 0.f, 0.f, 0.f};
#pragma unroll
        for (int kk = 0; kk < 2; ++kk)
#pragma unroll
            for (int i = 0; i < 4; ++i)
#pragma unroll
                for (int j = 0; j < 4; ++j)
                    acc[i][j] = __builtin_amdgcn_mfma_f32_16x16x32_bf16(
                        bfr[kk][j], afr[kk][i], acc[i][j], 0, 0, 0);

        // ---- in-register decay: 7 shared windows T[d], d = j-i+3 ----
        {
            float w  = weight[h];
            float lw = w > 0.f ? w : 0.01f * w;
            float scale = -lw * 1.44269504088896f;
            float fdy = (float)(2 * (tcol - trow) + (wc - wr));
            float dy2 = fdy * fdy;
            f32x4 T[7];
#pragma unroll
            for (int d = 0; d < 7; ++d) {
                float dx0 = (float)((d - 3) * 16 + kg * 4 - r16);
#pragma unroll
                for (int w_ = 0; w_ < 4; ++w_) {
                    float dx = dx0 + (float)w_;
                    float dist = __builtin_amdgcn_sqrtf(dx * dx + dy2);
                    T[d][w_] = __builtin_amdgcn_exp2f(scale * dist);
                }
            }
#pragma unroll
            for (int i = 0; i < 4; ++i)
#pragma unroll
                for (int j = 0; j < 4; ++j)
                    acc[i][j] *= T[j - i + 3];
        }

        // ---- prefetch next tile's fragments BEFORE this tile's stores ----
        if (t + 1 < TILES_PER_BLOCK)
            load_frags((t + 1) * PERS_BLOCKS + blockIdx.x);
        __builtin_amdgcn_sched_barrier(0);   // keep loads above the stores

        const size_t obase = (size_t)bh * SEQ * SEQ;
#pragma unroll
        for (int half = 0; half < 2; ++half) {
            // ---- stage half (64 rows) to LDS (swizzled) ----
            wg_barrier_lds();                // prev drain reads complete
#pragma unroll
            for (int ii = 0; ii < 2; ++ii) {
                const int i    = half * 2 + ii;
                const int lrow = wr * 32 + ii * 16 + r16;   // LDS row 0..63
#pragma unroll
                for (int j = 0; j < 4; ++j) {
                    int slot = (wc * 16 + j * 4 + kg) ^ (lrow & 7);
                    *reinterpret_cast<f32x4*>(&lds[lrow * 128 + slot * 4]) =
                        acc[i][j];
                }
            }
            wg_barrier_lds();                // stage visible to all waves

            // ---- drain: 8 instrs/wave, each 2 rows x 512 B contiguous ----
#pragma unroll
            for (int tI = 0; tI < 8; ++tI) {
                int lr = wave * 16 + tI * 2 + (lane >> 5);  // LDS row 0..63
                int slot = c32 ^ (lr & 7);
                f32x4 v = *reinterpret_cast<const f32x4*>(
                    &lds[lr * 128 + slot * 4]);
                int wr_ = lr >> 5;
                int i   = half * 2 + ((lr >> 4) & 1);
                int grow = brow0 + wr_ * 64 + i * 16 + (lr & 15);
                float* op = out + obase + (size_t)grow * SEQ + bcol0 + c32 * 4;
                *reinterpret_cast<f32x4*>(op) = v;          // plain store
            }
        }
    }
}

extern "C" void kernel_launch(void* const* d_in, const int* in_sizes, int n_in,
                              void* d_out, int out_size, void* d_ws, size_t ws_size,
                              hipStream_t stream) {
    const float* q  = (const float*)d_in[0];
    const float* b  = (const float*)d_in[1];
    const float* fr = (const float*)d_in[2];
    const float* wt = (const float*)d_in[3];
    float* out = (float*)d_out;

    const size_t need = 2 * TENSOR_ELEMS * sizeof(unsigned short);
    if (ws_size < need) return;

    rope_kernel<<<ROPE_BLOCKS, 256, 0, stream>>>(q, b, fr, (unsigned int*)d_ws);

    gemm_delta_kernel<<<PERS_BLOCKS, 256, 0, stream>>>(
        (const unsigned short*)d_ws, wt, out);
}

// Round 16
// 92.719 us; speedup vs baseline: 12.5851x; 2.1223x over previous
//
#include <hip/hip_runtime.h>
#include <hip/hip_bf16.h>

#define BQ   2
#define NH   12
#define SEQ  2048
#define DIM  64
#define EXQ  64   // end_x (both grids equal -> resample is identity)

#define TENSOR_ELEMS ((size_t)BQ * NH * SEQ * DIM)   // 3,145,728 bf16 each
#define ROPE_BLOCKS  6144                             // 2*BQ*NH*SEQ*16 / 256
#define PERS_BLOCKS  512                              // 2 blocks/CU exact
#define TILES_PER_BLOCK 12                            // 512*12 = 6144 tiles

typedef __attribute__((ext_vector_type(8))) short short8;
typedef __attribute__((ext_vector_type(4))) float f32x4;

static __device__ __forceinline__ unsigned int pk2bf(float lo, float hi) {
    union { float f; unsigned int u; } a, b; a.f = lo; b.f = hi;
    unsigned int rl = (a.u + 0x7fffu + ((a.u >> 16) & 1u)) >> 16;  // RNE
    unsigned int rh = (b.u + 0x7fffu + ((b.u >> 16) & 1u)) >> 16;
    return (rh << 16) | (rl & 0xffffu);
}

// barrier that does NOT drain vmcnt (plain __syncthreads emits vmcnt(0),
// which would stall on our fire-and-forget store stream)
static __device__ __forceinline__ void wg_barrier_lds() {
    asm volatile("s_waitcnt lgkmcnt(0)" ::: "memory");
    __builtin_amdgcn_s_barrier();
}

// ---- Phase 1: RoPE-rotate q,b -> bf16 ws (fast HW trig) --------------------
// ws layout: xq bf16[TENSOR_ELEMS] | xb bf16[TENSOR_ELEMS]
__global__ __launch_bounds__(256)
void rope_kernel(const float* __restrict__ qin,
                 const float* __restrict__ bin,
                 const float* __restrict__ freqs,   // [2, NH, 16]
                 unsigned int* __restrict__ ws_u32)
{
    int t  = blockIdx.x * 256 + threadIdx.x;
    int p4 = t & 15;                 // quad of elements (2 pairs)
    int n  = (t >> 4) & (SEQ - 1);
    int rest = t >> 15;              // (tensor*BQ+b)*NH + h
    int h    = rest % NH;
    int tb   = rest / NH;
    int tensor = tb >> 1;
    int b      = tb & 1;

    float tx = (float)(n & (EXQ - 1));
    float ty = (float)(n >> 6);

    int pr0 = 2 * p4;                // pair indices pr0, pr0+1
    float f0, f1;
    if (p4 < 8) {
        f0 = freqs[h * 16 + pr0] * tx;
        f1 = freqs[h * 16 + pr0 + 1] * tx;
    } else {
        f0 = freqs[NH * 16 + h * 16 + (pr0 - 16)] * ty;
        f1 = freqs[NH * 16 + h * 16 + (pr0 - 15)] * ty;
    }

    const float* src = tensor ? bin : qin;
    size_t off = ((size_t)(b * NH + h) * SEQ + n) * DIM + 4 * p4;
    float4 v = *reinterpret_cast<const float4*>(src + off);

    float s0 = __sinf(f0), c0 = __cosf(f0);   // v_sin/v_cos fast path
    float s1 = __sinf(f1), c1 = __cosf(f1);

    float o0 = v.x * c0 - v.y * s0;
    float o1 = v.x * s0 + v.y * c0;
    float o2 = v.z * c1 - v.w * s1;
    float o3 = v.z * s1 + v.w * c1;

    uint2 packed;
    packed.x = pk2bf(o0, o1);
    packed.y = pk2bf(o2, o3);
    size_t uidx = (size_t)tensor * (TENSOR_ELEMS / 2) + (off >> 1);
    *reinterpret_cast<uint2*>(ws_u32 + uidx) = packed;
}

// ---- Phase 2: persistent-block 128x128 MFMA GEMM + fused decay -------------
// ITERATION-MAJOR tile mapping: g = iter*512 + blockIdx. All 512 co-resident
// blocks process the same 2 heads per iteration, so each A/B panel is read by
// its 16 sharers CONCURRENTLY (~1 MB working set/iter -> L2/L3-resident) and
// HBM re-read traffic collapses to one 12.6 MB pass. Per tile: MFMA (swapped
// operands -> lane holds 4 consecutive cols), in-register decay via 7 (j-i)
// windows (raw v_sqrt/v_exp), 64 KB LDS transpose stage (XOR swizzle),
// lane-contiguous plain f32x4 stores, lgkm-only barriers,
// prefetch-before-stores.
__global__ __launch_bounds__(256, 2)
void gemm_delta_kernel(const unsigned short* __restrict__ ws,
                       const float* __restrict__ weight,
                       float* __restrict__ out)
{
    __shared__ float lds[128 * 128];      // 64 KB stage

    const int lane = threadIdx.x & 63;
    const int wave = threadIdx.x >> 6;
    const int wr   = wave >> 1, wc = wave & 1;
    const int r16  = lane & 15;
    const int kg   = lane >> 4;
    const int c32  = lane & 31;

    const unsigned short* xq = ws;
    const unsigned short* xb = ws + TENSOR_ELEMS;

    short8 afr[2][4], bfr[2][4];

    // ---- load fragments for tile g ----
    auto load_frags = [&](int g) {
        int bh = g >> 8, rem = g & 255;
        int trow = rem >> 4, tcol = rem & 15;
        const size_t base = (size_t)bh * SEQ * DIM;
        int row0 = trow * 128 + wr * 64;
        int col0 = tcol * 128 + wc * 64;
#pragma unroll
        for (int kk = 0; kk < 2; ++kk)
#pragma unroll
            for (int i = 0; i < 4; ++i) {
                int arw = row0 + i * 16 + r16;
                int bcl = col0 + i * 16 + r16;
                afr[kk][i] = *reinterpret_cast<const short8*>(
                    xq + base + (size_t)arw * DIM + kk * 32 + kg * 8);
                bfr[kk][i] = *reinterpret_cast<const short8*>(
                    xb + base + (size_t)bcl * DIM + kk * 32 + kg * 8);
            }
    };

    load_frags(blockIdx.x);

    for (int t = 0; t < TILES_PER_BLOCK; ++t) {
        const int g    = t * PERS_BLOCKS + blockIdx.x;   // iteration-major
        const int bh   = g >> 8, rem = g & 255;
        const int trow = rem >> 4, tcol = rem & 15;
        const int h    = bh % NH;
        const int brow0 = trow * 128, bcol0 = tcol * 128;

        // ---- MFMA ----
        f32x4 acc[4][4];
#pragma unroll
        for (int i = 0; i < 4; ++i)
#pragma unroll
            for (int j = 0; j < 4; ++j)
                acc[i][j] = (f32x4){0.f, 0.f, 0.f, 0.f};
#pragma unroll
        for (int kk = 0; kk < 2; ++kk)
#pragma unroll
            for (int i = 0; i < 4; ++i)
#pragma unroll
                for (int j = 0; j < 4; ++j)
                    acc[i][j] = __builtin_amdgcn_mfma_f32_16x16x32_bf16(
                        bfr[kk][j], afr[kk][i], acc[i][j], 0, 0, 0);

        // ---- in-register decay: 7 shared windows T[d], d = j-i+3 ----
        // window element w: dx = (d-3)*16 + kg*4 - r16 + w, dy wave-uniform
        {
            float w  = weight[h];
            float lw = w > 0.f ? w : 0.01f * w;
            float scale = -lw * 1.44269504088896f;
            float fdy = (float)(2 * (tcol - trow) + (wc - wr));
            float dy2 = fdy * fdy;
            f32x4 T[7];
#pragma unroll
            for (int d = 0; d < 7; ++d) {
                float dx0 = (float)((d - 3) * 16 + kg * 4 - r16);
#pragma unroll
                for (int w_ = 0; w_ < 4; ++w_) {
                    float dx = dx0 + (float)w_;
                    float dist = __builtin_amdgcn_sqrtf(dx * dx + dy2);
                    T[d][w_] = __builtin_amdgcn_exp2f(scale * dist);
                }
            }
#pragma unroll
            for (int i = 0; i < 4; ++i)
#pragma unroll
                for (int j = 0; j < 4; ++j)
                    acc[i][j] *= T[j - i + 3];
        }

        // ---- prefetch next tile's fragments BEFORE this tile's stores ----
        if (t + 1 < TILES_PER_BLOCK)
            load_frags((t + 1) * PERS_BLOCKS + blockIdx.x);
        __builtin_amdgcn_sched_barrier(0);   // keep loads above the stores

        // ---- stage to LDS (swizzled) ----
        wg_barrier_lds();                    // prev drain reads complete
#pragma unroll
        for (int i = 0; i < 4; ++i) {
            int lrow = wr * 64 + i * 16 + r16;       // 0..127
#pragma unroll
            for (int j = 0; j < 4; ++j) {
                int slot = (wc * 16 + j * 4 + kg) ^ (lrow & 7);
                *reinterpret_cast<f32x4*>(&lds[lrow * 128 + slot * 4]) = acc[i][j];
            }
        }
        wg_barrier_lds();                    // stage visible to all waves

        // ---- drain: 16 instrs/wave, each 2 rows x 512 B contiguous ----
        const size_t obase = (size_t)bh * SEQ * SEQ;
#pragma unroll
        for (int tI = 0; tI < 16; ++tI) {
            int lr = wave * 32 + tI * 2 + (lane >> 5);   // 0..127
            int slot = c32 ^ (lr & 7);
            f32x4 v = *reinterpret_cast<const f32x4*>(&lds[lr * 128 + slot * 4]);
            float* op = out + obase + (size_t)(brow0 + lr) * SEQ + bcol0 + c32 * 4;
            *reinterpret_cast<f32x4*>(op) = v;           // plain store
        }
    }
}

extern "C" void kernel_launch(void* const* d_in, const int* in_sizes, int n_in,
                              void* d_out, int out_size, void* d_ws, size_t ws_size,
                              hipStream_t stream) {
    const float* q  = (const float*)d_in[0];
    const float* b  = (const float*)d_in[1];
    const float* fr = (const float*)d_in[2];
    const float* wt = (const float*)d_in[3];
    float* out = (float*)d_out;

    const size_t need = 2 * TENSOR_ELEMS * sizeof(unsigned short);
    if (ws_size < need) return;

    rope_kernel<<<ROPE_BLOCKS, 256, 0, stream>>>(q, b, fr, (unsigned int*)d_ws);

    gemm_delta_kernel<<<PERS_BLOCKS, 256, 0, stream>>>(
        (const unsigned short*)d_ws, wt, out);
}